// Round 1
// baseline (436.778 us; speedup 1.0000x reference)
//
#include <hip/hip_runtime.h>
#include <hip/hip_bf16.h>

// Elementwise affine: out[i] = x[i] * 2 + 5, fp32, 8192*8192 = 64Mi elements.
// Pure HBM-bound (512 MB traffic, zero reuse). float4 vectorized, grid-stride.

__global__ __launch_bounds__(256) void affine_kernel(const float4* __restrict__ x,
                                                     float4* __restrict__ out,
                                                     int n4) {
    int stride = gridDim.x * blockDim.x;
    for (int i = blockIdx.x * blockDim.x + threadIdx.x; i < n4; i += stride) {
        float4 v = x[i];
        float4 r;
        r.x = fmaf(v.x, 2.0f, 5.0f);
        r.y = fmaf(v.y, 2.0f, 5.0f);
        r.z = fmaf(v.z, 2.0f, 5.0f);
        r.w = fmaf(v.w, 2.0f, 5.0f);
        out[i] = r;
    }
}

extern "C" void kernel_launch(void* const* d_in, const int* in_sizes, int n_in,
                              void* d_out, int out_size, void* d_ws, size_t ws_size,
                              hipStream_t stream) {
    const float4* x = (const float4*)d_in[0];
    float4* out = (float4*)d_out;
    int n4 = out_size / 4;  // 64Mi / 4 = 16Mi float4 (evenly divisible)

    // 256 CUs * 8 blocks/CU = 2048 blocks -> each thread iterates ~32 times,
    // amortizing address setup while keeping full occupancy.
    int block = 256;
    int grid = 2048;
    affine_kernel<<<grid, block, 0, stream>>>(x, out, n4);
}

// Round 2
// 412.625 us; speedup vs baseline: 1.0585x; 1.0585x over previous
//
#include <hip/hip_runtime.h>
#include <hip/hip_bf16.h>

// Elementwise affine: out[i] = x[i] * 2 + 5, fp32, 8192*8192 = 64Mi elements.
// Pure HBM-bound (512 MB traffic, zero reuse).
// m13-verified peak-BW pattern: one float4 per thread, huge grid, no loop —
// continuous block dispatch keeps HBM saturated without per-thread ILP.

__global__ __launch_bounds__(256) void affine_kernel(const float4* __restrict__ x,
                                                     float4* __restrict__ out) {
    int i = blockIdx.x * blockDim.x + threadIdx.x;
    float4 v = x[i];
    float4 r;
    r.x = fmaf(v.x, 2.0f, 5.0f);
    r.y = fmaf(v.y, 2.0f, 5.0f);
    r.z = fmaf(v.z, 2.0f, 5.0f);
    r.w = fmaf(v.w, 2.0f, 5.0f);
    out[i] = r;
}

extern "C" void kernel_launch(void* const* d_in, const int* in_sizes, int n_in,
                              void* d_out, int out_size, void* d_ws, size_t ws_size,
                              hipStream_t stream) {
    const float4* x = (const float4*)d_in[0];
    float4* out = (float4*)d_out;
    int n4 = out_size / 4;      // 16Mi float4, divides evenly: 16Mi/256 = 65536 blocks
    int block = 256;
    int grid = n4 / block;      // 65536
    affine_kernel<<<grid, block, 0, stream>>>(x, out);
}